// Round 15
// baseline (489.023 us; speedup 1.0000x reference)
//
#include <hip/hip_runtime.h>
#include <math.h>

#define DI __device__ __forceinline__

constexpr int Hh   = 128;
constexpr int Ww   = 128;
constexpr int WF   = 65;            // W/2+1
constexpr int NBIN = Hh * WF;       // 8320
constexpr int NB   = 32;            // batch
constexpr int CIN  = 64;
constexpr int COUT = 128;
constexpr int HO   = 120;
constexpr int WO   = 120;

typedef __bf16 bf16x8 __attribute__((ext_vector_type(8)));
typedef float  f32x16 __attribute__((ext_vector_type(16)));

// ---- bf16 pack/unpack (RNE) ----
DI unsigned int bfbits(float x) {
  unsigned int u = __float_as_uint(x);
  return (u + 0x7FFFu + ((u >> 16) & 1u)) >> 16;
}
DI unsigned int packbf(float re, float im) { return bfbits(re) | (bfbits(im) << 16); }
DI float2 unpackbf(unsigned int v) {
  return make_float2(__uint_as_float(v << 16), __uint_as_float(v & 0xFFFF0000u));
}

DI f32x16 MFMA32(uint4 a, uint4 b, f32x16 c) {
  return __builtin_amdgcn_mfma_f32_32x32x16_bf16(
      __builtin_bit_cast(bf16x8, a), __builtin_bit_cast(bf16x8, b), c, 0, 0, 0);
}
DI unsigned int rotneg(unsigned int x) { return ((x << 16) | (x >> 16)) ^ 0x80000000u; }
DI uint4 derive(uint4 s) {
  uint4 r; r.x = rotneg(s.x); r.y = rotneg(s.y); r.z = rotneg(s.z); r.w = rotneg(s.w);
  return r;
}

// LDS-only barrier: drains ds-ops (lgkmcnt) but leaves global loads (vmcnt)
// in flight across the barrier. sched_barrier fences (rule #18).
DI void lds_barrier() {
  __builtin_amdgcn_sched_barrier(0);
  asm volatile("s_waitcnt lgkmcnt(0)" ::: "memory");
  __builtin_amdgcn_sched_barrier(0);
  __builtin_amdgcn_s_barrier();
  __builtin_amdgcn_sched_barrier(0);
}

// ---------------------------------------------------------------------------
// Register/shuffle 128-pt DIF FFT (ILP-2), lane-select folded into per-lane
// constants. Lane l holds a=x[l], b=x[l+64].
// After: a = X[2*bitrev6(l)], b = X[2*bitrev6(l)+1].
// Inverse: conj in, same DIF, conj out.
// ---------------------------------------------------------------------------
DI int bitrev6(int l) {
  return ((l & 1) << 5) | ((l & 2) << 3) | ((l & 4) << 1) |
         ((l & 8) >> 1) | ((l & 16) >> 3) | ((l & 32) >> 5);
}
DI float2 cmul(float2 a, float2 b) {
  return make_float2(a.x * b.x - a.y * b.y, a.x * b.y + a.y * b.x);
}
DI float2 sxor(float2 v, int m) {
  return make_float2(__shfl_xor(v.x, m), __shfl_xor(v.y, m));
}
DI float bpermf(int addr, float v) {
  return __int_as_float(__builtin_amdgcn_ds_bpermute(addr, __float_as_int(v)));
}

struct FftCtx {
  float2 tw0;       // W128^l (stage h=64, both outputs kept)
  float2 tws[5];    // per-lane selected twiddle, stages h=32,16,8,4,2
  float  sgn[5];    // +1 on sum-lanes, -1 on diff-lanes
  float  sgn1;      // stage h=1
};
DI void twinit(FftCtx& c, int l) {
  float s_, c_;
  __sincosf(-(float)M_PI * (float)l / 64.f, &s_, &c_);
  c.tw0 = make_float2(c_, s_);
#pragma unroll
  for (int i = 0; i < 5; ++i) {
    const int h = 32 >> i;
    __sincosf(-(float)M_PI * (float)(l & (h - 1)) / (float)h, &s_, &c_);
    const bool hi = (l & h) != 0;
    c.tws[i] = hi ? make_float2(c_, s_) : make_float2(1.f, 0.f);
    c.sgn[i] = hi ? -1.f : 1.f;
  }
  c.sgn1 = (l & 1) ? -1.f : 1.f;
}
DI void stgf(float2& v, int m, float2 tw, float sgn) {
  float2 p = sxor(v, m);
  float2 t = make_float2(fmaf(sgn, v.x, p.x), fmaf(sgn, v.y, p.y));
  v = cmul(t, tw);
}
DI void stg1f(float2& v, float sgn) {
  float2 p = sxor(v, 1);
  v = make_float2(fmaf(sgn, v.x, p.x), fmaf(sgn, v.y, p.y));
}
DI void sfft128x2(float2& a0, float2& b0, float2& a1, float2& b1,
                  const FftCtx& c) {
  {
    float2 s = make_float2(a0.x + b0.x, a0.y + b0.y);
    float2 d = make_float2(a0.x - b0.x, a0.y - b0.y);
    a0 = s; b0 = cmul(d, c.tw0);
  }
  {
    float2 s = make_float2(a1.x + b1.x, a1.y + b1.y);
    float2 d = make_float2(a1.x - b1.x, a1.y - b1.y);
    a1 = s; b1 = cmul(d, c.tw0);
  }
#pragma unroll
  for (int i = 0; i < 5; ++i) {
    const int h = 32 >> i;
    stgf(a0, h, c.tws[i], c.sgn[i]); stgf(a1, h, c.tws[i], c.sgn[i]);
    stgf(b0, h, c.tws[i], c.sgn[i]); stgf(b1, h, c.tws[i], c.sgn[i]);
  }
  stg1f(a0, c.sgn1); stg1f(a1, c.sgn1); stg1f(b0, c.sgn1); stg1f(b1, c.sgn1);
}

// ---------------------------------------------------------------------------
// Forward: one block (256 thr) per (b, i). real 128x128 -> bf16 complex 128x65.
// rfft unpack fully in-register via ds_bpermute. (FROZEN)
// ---------------------------------------------------------------------------
__global__ __launch_bounds__(256) void fwd_fft(const float* __restrict__ sig,
                                               unsigned int* __restrict__ sf) {
  __shared__ unsigned int sImg[NBIN];                       // 33280 B

  const int t = threadIdx.x, grp = t >> 6, l = t & 63;
  const size_t img = blockIdx.x;
  const float* src = sig + img * (size_t)(Hh * Ww);
  unsigned int* dst = sf + img * (size_t)NBIN;

  FftCtx ctx; twinit(ctx, l);
  const int br = bitrev6(l);
  const int sk4 = bitrev6(l >> 1) * 4;                 // holder of Z[l]
  const int im  = (128 - l) & 127;
  const int sm4 = bitrev6(im >> 1) * 4;                // holder of Z[128-l]
  const bool podd = (l & 1) != 0;

  // ---- phase 1: row rfft (two real rows per complex FFT), ILP-2 ----
  for (int batch = 0; batch < 8; ++batch) {
    float2 a[2], b[2];
#pragma unroll
    for (int f = 0; f < 2; ++f) {
      const int jp = batch * 8 + grp * 2 + f;               // row pair 0..63
      const float* r0 = src + (size_t)(2 * jp) * Ww;
      a[f] = make_float2(r0[l],      r0[Ww + l]);
      b[f] = make_float2(r0[64 + l], r0[Ww + 64 + l]);
    }
    sfft128x2(a[0], b[0], a[1], b[1], ctx);
#pragma unroll
    for (int f = 0; f < 2; ++f) {
      const int jp = batch * 8 + grp * 2 + f;
      float axk = bpermf(sk4, a[f].x), ayk = bpermf(sk4, a[f].y);
      float bxk = bpermf(sk4, b[f].x), byk = bpermf(sk4, b[f].y);
      float axm = bpermf(sm4, a[f].x), aym = bpermf(sm4, a[f].y);
      float bxm = bpermf(sm4, b[f].x), bym = bpermf(sm4, b[f].y);
      float z64x = bpermf(4, a[f].x),  z64y = bpermf(4, a[f].y);   // Z[64] in lane 1.a
      float2 Zk = podd ? make_float2(bxk, byk) : make_float2(axk, ayk);
      float2 Zm = podd ? make_float2(bxm, bym) : make_float2(axm, aym);
      sImg[(2 * jp) * WF + l]     = packbf(0.5f * (Zk.x + Zm.x), 0.5f * (Zk.y - Zm.y));
      sImg[(2 * jp + 1) * WF + l] = packbf(0.5f * (Zk.y + Zm.y), 0.5f * (Zm.x - Zk.x));
      if (l == 0) {
        sImg[(2 * jp) * WF + 64]     = packbf(z64x, 0.f);
        sImg[(2 * jp + 1) * WF + 64] = packbf(z64y, 0.f);
      }
    }
  }
  __syncthreads();

  // ---- phase 2: complex FFT along H per column, in-register ----
  for (int batch = 0; batch < 9; ++batch) {
    float2 a[2], b[2]; int wcol[2];
#pragma unroll
    for (int f = 0; f < 2; ++f) {
      const int w = batch * 8 + grp * 2 + f; wcol[f] = w;
      const int wc = (w < WF) ? w : (WF - 1);
      a[f] = unpackbf(sImg[l * WF + wc]);
      b[f] = unpackbf(sImg[(l + 64) * WF + wc]);
    }
    sfft128x2(a[0], b[0], a[1], b[1], ctx);
#pragma unroll
    for (int f = 0; f < 2; ++f) {
      if (wcol[f] < WF) {
        sImg[(2 * br) * WF + wcol[f]]     = packbf(a[f].x, a[f].y);
        sImg[(2 * br + 1) * WF + wcol[f]] = packbf(b[f].x, b[f].y);
      }
    }
  }
  __syncthreads();

  const uint4* s4 = (const uint4*)sImg;
  uint4* d4 = (uint4*)dst;
  for (int idx = t; idx < NBIN / 4; idx += 256) d4[idx] = s4[idx];
}

// ---------------------------------------------------------------------------
// Spectral contraction via 32x32x16 MFMA. r13 geometry, now DOUBLE-BUFFERED:
// PLANE 256 -> 2 bufs x (wbuf+sbuf) = exactly 64 KB. One lds_barrier per
// chunk; pack(k+1) writes the opposite buffer from in-flight MFMA(k) reads,
// so pack overlaps other waves' MFMA. 1-deep prefetch, single register set.
// ---------------------------------------------------------------------------
constexpr int PT    = 16;
constexpr int PLANE = 256;

__global__ __launch_bounds__(512, 4) void spec_mm(const unsigned int* __restrict__ sf,
                                                  const float* __restrict__ wr,
                                                  const float* __restrict__ wi,
                                                  unsigned int* __restrict__ of) {
  __shared__ unsigned int wbuf[2][PT * PLANE];   // 16 KB each
  __shared__ unsigned int sbuf[2][PT * PLANE];

  const int t = threadIdx.x;
  const int bid = blockIdx.x;
  const int swz = (bid & 7) * 260 + (bid >> 3);
  const int o0 = (swz & 3) * 32;
  const int p0 = (swz >> 2) * PT;

  const int po = t & 3;
  const int ii = (t >> 2) & 7;
  const int rl = (t >> 5) & 15;

  const float* wrp0 = wr + ((size_t)(o0 + rl) * CIN + ii) * NBIN + p0 + po * 4;
  const float* wip0 = wi + ((size_t)(o0 + rl) * CIN + ii) * NBIN + p0 + po * 4;
  const unsigned int* sfp0 = sf + ((size_t)rl * CIN + ii) * NBIN + p0 + po * 4;
  const size_t rowAdv = (size_t)16 * CIN * NBIN;

  auto slotOf = [](int row, int i) {
    return ((((row * 2) + (i >> 2)) ^ ((row >> 2) & 7)) << 2) + (i & 3);
  };
  const int slotLo = slotOf(rl, ii);
  const int slotHi = slotOf(rl + 16, ii);

  const int l = t & 63, wv = t >> 6;
  const int lr = l & 31, lq = l >> 5;
  const int moff = ((((lr * 2) + lq) ^ ((lr >> 2) & 7)) << 2);
  const int pA = 2 * wv, pB = 2 * wv + 1;

  f32x16 aR0 = {}, aI0 = {}, aR1 = {}, aI1 = {};

  float4 w0r, w1r, w0i, w1i; uint4 s0v, s1v;

  auto LOAD = [&](int kq) {
    const size_t adv = (size_t)kq * 8 * NBIN;
    w0r = *(const float4*)(wrp0 + adv);  w1r = *(const float4*)(wrp0 + adv + rowAdv);
    w0i = *(const float4*)(wip0 + adv);  w1i = *(const float4*)(wip0 + adv + rowAdv);
    s0v = *(const uint4*)(sfp0 + adv);   s1v = *(const uint4*)(sfp0 + adv + rowAdv);
  };
  auto PACK = [&](int buf) {
    const float* a0 = (const float*)&w0r;  const float* a1 = (const float*)&w1r;
    const float* b0 = (const float*)&w0i;  const float* b1 = (const float*)&w1i;
    const unsigned int* u0 = (const unsigned int*)&s0v;
    const unsigned int* u1 = (const unsigned int*)&s1v;
#pragma unroll
    for (int j = 0; j < 4; ++j) {
      const int pp = (po * 4 + j) * PLANE;
      wbuf[buf][pp + slotLo] = packbf(a0[j], -b0[j]);
      wbuf[buf][pp + slotHi] = packbf(a1[j], -b1[j]);
      sbuf[buf][pp + slotLo] = u0[j];
      sbuf[buf][pp + slotHi] = u1[j];
    }
  };
  auto MF = [&](int buf) {
    {
      const uint4 a = *(const uint4*)&wbuf[buf][pA * PLANE + moff];
      const uint4 s = *(const uint4*)&sbuf[buf][pA * PLANE + moff];
      aR0 = MFMA32(a, s, aR0);
      aI0 = MFMA32(a, derive(s), aI0);
    }
    {
      const uint4 a = *(const uint4*)&wbuf[buf][pB * PLANE + moff];
      const uint4 s = *(const uint4*)&sbuf[buf][pB * PLANE + moff];
      aR1 = MFMA32(a, s, aR1);
      aI1 = MFMA32(a, derive(s), aI1);
    }
  };

  // prologue
  LOAD(0);
  PACK(0);                 // vmcnt wait on chunk 0 (one-time exposed latency)
  LOAD(1);                 // chunk 1 in flight across the barrier
  lds_barrier();

  for (int kq = 0; kq < 8; ++kq) {
    MF(kq & 1);            // reads buf[kq&1]
    if (kq < 7) {
      PACK((kq + 1) & 1);  // writes the OTHER buffer (overlaps others' MFMA)
      if (kq < 6) LOAD(kq + 2);
      lds_barrier();       // one barrier per chunk
    }
  }

  const int b = lr;
#pragma unroll
  for (int r = 0; r < 16; ++r) {
    const int o = o0 + (r & 3) + 8 * (r >> 2) + 4 * lq;
    uint2 v;
    v.x = packbf(aR0[r], aI0[r]);
    v.y = packbf(aR1[r], aI1[r]);
    *(uint2*)(of + ((size_t)b * COUT + o) * NBIN + p0 + 2 * wv) = v;
  }
}

// ---------------------------------------------------------------------------
// Inverse: one block (256 thr) per (b, o). bf16 128x65 -> real 120x120 (+bias).
// y = conj(DIF(conj z)) / 16384; rows write straight to global. (FROZEN)
// ---------------------------------------------------------------------------
__global__ __launch_bounds__(256) void inv_fft(const unsigned int* __restrict__ of,
                                               const float* __restrict__ bias,
                                               float* __restrict__ out) {
  __shared__ unsigned int sImg[NBIN];

  const int t = threadIdx.x, grp = t >> 6, l = t & 63;
  const size_t img = blockIdx.x;                 // b*COUT + o
  const unsigned int* src = of + img * (size_t)NBIN;
  float* dst = out + img * (size_t)(HO * WO);
  const float bo = bias[img & (COUT - 1)];

  FftCtx ctx; twinit(ctx, l);
  const int br = bitrev6(l);

  const uint4* s4 = (const uint4*)src;
  uint4* d4 = (uint4*)sImg;
  for (int idx = t; idx < NBIN / 4; idx += 256) d4[idx] = s4[idx];
  __syncthreads();

  // ---- phase 1: inverse FFT along H per column (unscaled) ----
  for (int batch = 0; batch < 9; ++batch) {
    float2 a[2], b[2]; int wcol[2];
#pragma unroll
    for (int f = 0; f < 2; ++f) {
      const int w = batch * 8 + grp * 2 + f; wcol[f] = w;
      const int wc = (w < WF) ? w : (WF - 1);
      float2 za = unpackbf(sImg[l * WF + wc]);
      float2 zb = unpackbf(sImg[(l + 64) * WF + wc]);
      a[f] = make_float2(za.x, -za.y);           // conj in
      b[f] = make_float2(zb.x, -zb.y);
    }
    sfft128x2(a[0], b[0], a[1], b[1], ctx);
#pragma unroll
    for (int f = 0; f < 2; ++f) {
      if (wcol[f] < WF) {
        sImg[(2 * br) * WF + wcol[f]]     = packbf(a[f].x, -a[f].y);   // conj out
        sImg[(2 * br + 1) * WF + wcol[f]] = packbf(b[f].x, -b[f].y);
      }
    }
  }
  __syncthreads();

  // ---- phase 2: irfft rows (pair trick) -> crop -> scale -> +bias ----
  const float sc = 1.f / 16384.f;
  for (int batch = 0; batch < 8; ++batch) {      // row pairs 0..59 (+4 pad)
    float2 a[2], b[2]; int jpv[2];
#pragma unroll
    for (int f = 0; f < 2; ++f) {
      const int jp = batch * 8 + grp * 2 + f; jpv[f] = jp;
      const int jc = (jp < 60) ? jp : 59;
      const unsigned int* X0p = &sImg[(size_t)(2 * jc) * WF];
      const unsigned int* X1p = X0p + WF;
      float2 za, zb;
      if (l == 0) {
        za = make_float2(unpackbf(X0p[0]).x,  unpackbf(X1p[0]).x);    // DC
        zb = make_float2(unpackbf(X0p[64]).x, unpackbf(X1p[64]).x);   // Nyquist
      } else {
        float2 x0 = unpackbf(X0p[l]), x1 = unpackbf(X1p[l]);
        za = make_float2(x0.x - x1.y, x0.y + x1.x);                   // Z[l]
        const int mI = 64 - l;
        float2 y0 = unpackbf(X0p[mI]), y1 = unpackbf(X1p[mI]);
        zb = make_float2(y0.x + y1.y, y1.x - y0.y);                   // Z[64+l]
      }
      a[f] = make_float2(za.x, -za.y);           // conj in
      b[f] = make_float2(zb.x, -zb.y);
    }
    sfft128x2(a[0], b[0], a[1], b[1], ctx);
    const int n0 = 2 * br;
#pragma unroll
    for (int f = 0; f < 2; ++f) {
      const int jp = jpv[f];
      if (jp < 60 && n0 < WO) {
        // y[n] = conj(out): row0 = Re, row1 = -Im
        float2 r0 = make_float2(a[f].x * sc + bo,  b[f].x * sc + bo);
        float2 r1 = make_float2(-a[f].y * sc + bo, -b[f].y * sc + bo);
        *(float2*)(dst + (size_t)(2 * jp) * WO + n0)     = r0;
        *(float2*)(dst + (size_t)(2 * jp + 1) * WO + n0) = r1;
      }
    }
  }
}

// ---------------------------------------------------------------------------
extern "C" void kernel_launch(void* const* d_in, const int* in_sizes, int n_in,
                              void* d_out, int out_size, void* d_ws, size_t ws_size,
                              hipStream_t stream) {
  const float* signal = (const float*)d_in[0];
  const float* wr     = (const float*)d_in[1];
  const float* wi     = (const float*)d_in[2];
  const float* bias   = (const float*)d_in[3];
  float* out = (float*)d_out;

  unsigned int* sig_fr = (unsigned int*)d_out;   // 68.2 MB, dead before inv writes
  unsigned int* out_fr = (unsigned int*)d_ws;    // 136.3 MB
  (void)in_sizes; (void)n_in; (void)out_size; (void)ws_size;

  fwd_fft<<<NB * CIN, 256, 0, stream>>>(signal, sig_fr);
  spec_mm<<<2080, 512, 0, stream>>>(sig_fr, wr, wi, out_fr);
  inv_fft<<<NB * COUT, 256, 0, stream>>>(out_fr, bias, out);
}

// Round 16
// 485.267 us; speedup vs baseline: 1.0077x; 1.0077x over previous
//
#include <hip/hip_runtime.h>
#include <math.h>

#define DI __device__ __forceinline__

constexpr int Hh   = 128;
constexpr int Ww   = 128;
constexpr int WF   = 65;            // W/2+1
constexpr int NBIN = Hh * WF;       // 8320
constexpr int NB   = 32;            // batch
constexpr int CIN  = 64;
constexpr int COUT = 128;
constexpr int HO   = 120;
constexpr int WO   = 120;

typedef __bf16 bf16x8 __attribute__((ext_vector_type(8)));
typedef float  f32x16 __attribute__((ext_vector_type(16)));

// ---- bf16 pack/unpack (RNE) ----
DI unsigned int bfbits(float x) {
  unsigned int u = __float_as_uint(x);
  return (u + 0x7FFFu + ((u >> 16) & 1u)) >> 16;
}
DI unsigned int packbf(float re, float im) { return bfbits(re) | (bfbits(im) << 16); }
DI float2 unpackbf(unsigned int v) {
  return make_float2(__uint_as_float(v << 16), __uint_as_float(v & 0xFFFF0000u));
}

DI f32x16 MFMA32(uint4 a, uint4 b, f32x16 c) {
  return __builtin_amdgcn_mfma_f32_32x32x16_bf16(
      __builtin_bit_cast(bf16x8, a), __builtin_bit_cast(bf16x8, b), c, 0, 0, 0);
}
DI unsigned int rotneg(unsigned int x) { return ((x << 16) | (x >> 16)) ^ 0x80000000u; }
DI uint4 derive(uint4 s) {
  uint4 r; r.x = rotneg(s.x); r.y = rotneg(s.y); r.z = rotneg(s.z); r.w = rotneg(s.w);
  return r;
}

// LDS-only barrier: drains ds-ops (lgkmcnt) but leaves global loads (vmcnt)
// in flight across the barrier. sched_barrier fences (rule #18).
DI void lds_barrier() {
  __builtin_amdgcn_sched_barrier(0);
  asm volatile("s_waitcnt lgkmcnt(0)" ::: "memory");
  __builtin_amdgcn_sched_barrier(0);
  __builtin_amdgcn_s_barrier();
  __builtin_amdgcn_sched_barrier(0);
}

// ---------------------------------------------------------------------------
// Register/shuffle 128-pt DIF FFT (ILP-2), lane-select folded into per-lane
// constants. Lane l holds a=x[l], b=x[l+64].
// After: a = X[2*bitrev6(l)], b = X[2*bitrev6(l)+1].
// Inverse: conj in, same DIF, conj out.
// ---------------------------------------------------------------------------
DI int bitrev6(int l) {
  return ((l & 1) << 5) | ((l & 2) << 3) | ((l & 4) << 1) |
         ((l & 8) >> 1) | ((l & 16) >> 3) | ((l & 32) >> 5);
}
DI float2 cmul(float2 a, float2 b) {
  return make_float2(a.x * b.x - a.y * b.y, a.x * b.y + a.y * b.x);
}
DI float2 sxor(float2 v, int m) {
  return make_float2(__shfl_xor(v.x, m), __shfl_xor(v.y, m));
}
DI float bpermf(int addr, float v) {
  return __int_as_float(__builtin_amdgcn_ds_bpermute(addr, __float_as_int(v)));
}

struct FftCtx {
  float2 tw0;       // W128^l (stage h=64, both outputs kept)
  float2 tws[5];    // per-lane selected twiddle, stages h=32,16,8,4,2
  float  sgn[5];    // +1 on sum-lanes, -1 on diff-lanes
  float  sgn1;      // stage h=1
};
DI void twinit(FftCtx& c, int l) {
  float s_, c_;
  __sincosf(-(float)M_PI * (float)l / 64.f, &s_, &c_);
  c.tw0 = make_float2(c_, s_);
#pragma unroll
  for (int i = 0; i < 5; ++i) {
    const int h = 32 >> i;
    __sincosf(-(float)M_PI * (float)(l & (h - 1)) / (float)h, &s_, &c_);
    const bool hi = (l & h) != 0;
    c.tws[i] = hi ? make_float2(c_, s_) : make_float2(1.f, 0.f);
    c.sgn[i] = hi ? -1.f : 1.f;
  }
  c.sgn1 = (l & 1) ? -1.f : 1.f;
}
DI void stgf(float2& v, int m, float2 tw, float sgn) {
  float2 p = sxor(v, m);
  float2 t = make_float2(fmaf(sgn, v.x, p.x), fmaf(sgn, v.y, p.y));
  v = cmul(t, tw);
}
DI void stg1f(float2& v, float sgn) {
  float2 p = sxor(v, 1);
  v = make_float2(fmaf(sgn, v.x, p.x), fmaf(sgn, v.y, p.y));
}
DI void sfft128x2(float2& a0, float2& b0, float2& a1, float2& b1,
                  const FftCtx& c) {
  {
    float2 s = make_float2(a0.x + b0.x, a0.y + b0.y);
    float2 d = make_float2(a0.x - b0.x, a0.y - b0.y);
    a0 = s; b0 = cmul(d, c.tw0);
  }
  {
    float2 s = make_float2(a1.x + b1.x, a1.y + b1.y);
    float2 d = make_float2(a1.x - b1.x, a1.y - b1.y);
    a1 = s; b1 = cmul(d, c.tw0);
  }
#pragma unroll
  for (int i = 0; i < 5; ++i) {
    const int h = 32 >> i;
    stgf(a0, h, c.tws[i], c.sgn[i]); stgf(a1, h, c.tws[i], c.sgn[i]);
    stgf(b0, h, c.tws[i], c.sgn[i]); stgf(b1, h, c.tws[i], c.sgn[i]);
  }
  stg1f(a0, c.sgn1); stg1f(a1, c.sgn1); stg1f(b0, c.sgn1); stg1f(b1, c.sgn1);
}

// ---------------------------------------------------------------------------
// Forward: one block (256 thr) per (b, i). real 128x128 -> bf16 complex 128x65.
// rfft unpack fully in-register via ds_bpermute. (FROZEN)
// ---------------------------------------------------------------------------
__global__ __launch_bounds__(256) void fwd_fft(const float* __restrict__ sig,
                                               unsigned int* __restrict__ sf) {
  __shared__ unsigned int sImg[NBIN];                       // 33280 B

  const int t = threadIdx.x, grp = t >> 6, l = t & 63;
  const size_t img = blockIdx.x;
  const float* src = sig + img * (size_t)(Hh * Ww);
  unsigned int* dst = sf + img * (size_t)NBIN;

  FftCtx ctx; twinit(ctx, l);
  const int br = bitrev6(l);
  const int sk4 = bitrev6(l >> 1) * 4;                 // holder of Z[l]
  const int im  = (128 - l) & 127;
  const int sm4 = bitrev6(im >> 1) * 4;                // holder of Z[128-l]
  const bool podd = (l & 1) != 0;

  // ---- phase 1: row rfft (two real rows per complex FFT), ILP-2 ----
  for (int batch = 0; batch < 8; ++batch) {
    float2 a[2], b[2];
#pragma unroll
    for (int f = 0; f < 2; ++f) {
      const int jp = batch * 8 + grp * 2 + f;               // row pair 0..63
      const float* r0 = src + (size_t)(2 * jp) * Ww;
      a[f] = make_float2(r0[l],      r0[Ww + l]);
      b[f] = make_float2(r0[64 + l], r0[Ww + 64 + l]);
    }
    sfft128x2(a[0], b[0], a[1], b[1], ctx);
#pragma unroll
    for (int f = 0; f < 2; ++f) {
      const int jp = batch * 8 + grp * 2 + f;
      float axk = bpermf(sk4, a[f].x), ayk = bpermf(sk4, a[f].y);
      float bxk = bpermf(sk4, b[f].x), byk = bpermf(sk4, b[f].y);
      float axm = bpermf(sm4, a[f].x), aym = bpermf(sm4, a[f].y);
      float bxm = bpermf(sm4, b[f].x), bym = bpermf(sm4, b[f].y);
      float z64x = bpermf(4, a[f].x),  z64y = bpermf(4, a[f].y);   // Z[64] in lane 1.a
      float2 Zk = podd ? make_float2(bxk, byk) : make_float2(axk, ayk);
      float2 Zm = podd ? make_float2(bxm, bym) : make_float2(axm, aym);
      sImg[(2 * jp) * WF + l]     = packbf(0.5f * (Zk.x + Zm.x), 0.5f * (Zk.y - Zm.y));
      sImg[(2 * jp + 1) * WF + l] = packbf(0.5f * (Zk.y + Zm.y), 0.5f * (Zm.x - Zk.x));
      if (l == 0) {
        sImg[(2 * jp) * WF + 64]     = packbf(z64x, 0.f);
        sImg[(2 * jp + 1) * WF + 64] = packbf(z64y, 0.f);
      }
    }
  }
  __syncthreads();

  // ---- phase 2: complex FFT along H per column, in-register ----
  for (int batch = 0; batch < 9; ++batch) {
    float2 a[2], b[2]; int wcol[2];
#pragma unroll
    for (int f = 0; f < 2; ++f) {
      const int w = batch * 8 + grp * 2 + f; wcol[f] = w;
      const int wc = (w < WF) ? w : (WF - 1);
      a[f] = unpackbf(sImg[l * WF + wc]);
      b[f] = unpackbf(sImg[(l + 64) * WF + wc]);
    }
    sfft128x2(a[0], b[0], a[1], b[1], ctx);
#pragma unroll
    for (int f = 0; f < 2; ++f) {
      if (wcol[f] < WF) {
        sImg[(2 * br) * WF + wcol[f]]     = packbf(a[f].x, a[f].y);
        sImg[(2 * br + 1) * WF + wcol[f]] = packbf(b[f].x, b[f].y);
      }
    }
  }
  __syncthreads();

  const uint4* s4 = (const uint4*)sImg;
  uint4* d4 = (uint4*)dst;
  for (int idx = t; idx < NBIN / 4; idx += 256) d4[idx] = s4[idx];
}

// ---------------------------------------------------------------------------
// Spectral contraction via 32x32x16 MFMA (r13 geometry, FROZEN) with a
// DRAM-locality task order: p varies FASTEST within an XCD, so each XCD
// sweeps one o-tile's weight array in memory order (2-8 KB sequential
// windows per (o,i) row instead of 512 B across 4x the streams).
// ---------------------------------------------------------------------------
constexpr int PT    = 16;
constexpr int PLANE = 260;

__global__ __launch_bounds__(512, 4) void spec_mm(const unsigned int* __restrict__ sf,
                                                  const float* __restrict__ wr,
                                                  const float* __restrict__ wi,
                                                  unsigned int* __restrict__ of) {
  __shared__ unsigned int wbuf[PT * PLANE];
  __shared__ unsigned int sbuf[PT * PLANE];

  const int t = threadIdx.x;
  const int bid = blockIdx.x;
  // XCD = bid&7; within an XCD, k = bid>>3 is sequential 0..259.
  // o-tile slowest (fixed per half-XCD-range), p fastest -> sequential sweep.
  const int swz = (bid & 7) * 260 + (bid >> 3);
  const int o0 = (swz / 520) * 32;
  const int p0 = (swz % 520) * PT;

  const int po = t & 3;
  const int ii = (t >> 2) & 7;
  const int rl = (t >> 5) & 15;

  const float* wrp0 = wr + ((size_t)(o0 + rl) * CIN + ii) * NBIN + p0 + po * 4;
  const float* wip0 = wi + ((size_t)(o0 + rl) * CIN + ii) * NBIN + p0 + po * 4;
  const unsigned int* sfp0 = sf + ((size_t)rl * CIN + ii) * NBIN + p0 + po * 4;
  const size_t rowAdv = (size_t)16 * CIN * NBIN;

  auto slotOf = [](int row, int i) {
    return ((((row * 2) + (i >> 2)) ^ ((row >> 2) & 7)) << 2) + (i & 3);
  };
  const int slotLo = slotOf(rl, ii);
  const int slotHi = slotOf(rl + 16, ii);

  const int l = t & 63, wv = t >> 6;
  const int lr = l & 31, lq = l >> 5;
  const int moff = ((((lr * 2) + lq) ^ ((lr >> 2) & 7)) << 2);
  const int pA = 2 * wv, pB = 2 * wv + 1;

  f32x16 aR0 = {}, aI0 = {}, aR1 = {}, aI1 = {};

  float4 w0r, w1r, w0i, w1i; uint4 s0v, s1v;
  {
    w0r = *(const float4*)(wrp0);          w1r = *(const float4*)(wrp0 + rowAdv);
    w0i = *(const float4*)(wip0);          w1i = *(const float4*)(wip0 + rowAdv);
    s0v = *(const uint4*)(sfp0);           s1v = *(const uint4*)(sfp0 + rowAdv);
  }

  for (int kq = 0; kq < 8; ++kq) {
    // ---- pack current chunk regs -> LDS ----
    const float* a0 = (const float*)&w0r;  const float* a1 = (const float*)&w1r;
    const float* b0 = (const float*)&w0i;  const float* b1 = (const float*)&w1i;
    const unsigned int* u0 = (const unsigned int*)&s0v;
    const unsigned int* u1 = (const unsigned int*)&s1v;
#pragma unroll
    for (int j = 0; j < 4; ++j) {
      const int pp = (po * 4 + j) * PLANE;
      wbuf[pp + slotLo] = packbf(a0[j], -b0[j]);
      wbuf[pp + slotHi] = packbf(a1[j], -b1[j]);
      sbuf[pp + slotLo] = u0[j];
      sbuf[pp + slotHi] = u1[j];
    }
    // ---- issue next chunk's loads; stay in flight across barriers ----
    if (kq < 7) {
      const size_t adv = (size_t)(kq + 1) * 8 * NBIN;
      w0r = *(const float4*)(wrp0 + adv);  w1r = *(const float4*)(wrp0 + adv + rowAdv);
      w0i = *(const float4*)(wip0 + adv);  w1i = *(const float4*)(wip0 + adv + rowAdv);
      s0v = *(const uint4*)(sfp0 + adv);   s1v = *(const uint4*)(sfp0 + adv + rowAdv);
    }
    lds_barrier();

    {
      const uint4 a = *(const uint4*)&wbuf[pA * PLANE + moff];
      const uint4 s = *(const uint4*)&sbuf[pA * PLANE + moff];
      aR0 = MFMA32(a, s, aR0);
      aI0 = MFMA32(a, derive(s), aI0);
    }
    {
      const uint4 a = *(const uint4*)&wbuf[pB * PLANE + moff];
      const uint4 s = *(const uint4*)&sbuf[pB * PLANE + moff];
      aR1 = MFMA32(a, s, aR1);
      aI1 = MFMA32(a, derive(s), aI1);
    }
    lds_barrier();
  }

  const int b = lr;
#pragma unroll
  for (int r = 0; r < 16; ++r) {
    const int o = o0 + (r & 3) + 8 * (r >> 2) + 4 * lq;
    uint2 v;
    v.x = packbf(aR0[r], aI0[r]);
    v.y = packbf(aR1[r], aI1[r]);
    *(uint2*)(of + ((size_t)b * COUT + o) * NBIN + p0 + 2 * wv) = v;
  }
}

// ---------------------------------------------------------------------------
// Inverse: one block (256 thr) per (b, o). bf16 128x65 -> real 120x120 (+bias).
// y = conj(DIF(conj z)) / 16384; rows write straight to global. (FROZEN)
// ---------------------------------------------------------------------------
__global__ __launch_bounds__(256) void inv_fft(const unsigned int* __restrict__ of,
                                               const float* __restrict__ bias,
                                               float* __restrict__ out) {
  __shared__ unsigned int sImg[NBIN];

  const int t = threadIdx.x, grp = t >> 6, l = t & 63;
  const size_t img = blockIdx.x;                 // b*COUT + o
  const unsigned int* src = of + img * (size_t)NBIN;
  float* dst = out + img * (size_t)(HO * WO);
  const float bo = bias[img & (COUT - 1)];

  FftCtx ctx; twinit(ctx, l);
  const int br = bitrev6(l);

  const uint4* s4 = (const uint4*)src;
  uint4* d4 = (uint4*)sImg;
  for (int idx = t; idx < NBIN / 4; idx += 256) d4[idx] = s4[idx];
  __syncthreads();

  // ---- phase 1: inverse FFT along H per column (unscaled) ----
  for (int batch = 0; batch < 9; ++batch) {
    float2 a[2], b[2]; int wcol[2];
#pragma unroll
    for (int f = 0; f < 2; ++f) {
      const int w = batch * 8 + grp * 2 + f; wcol[f] = w;
      const int wc = (w < WF) ? w : (WF - 1);
      float2 za = unpackbf(sImg[l * WF + wc]);
      float2 zb = unpackbf(sImg[(l + 64) * WF + wc]);
      a[f] = make_float2(za.x, -za.y);           // conj in
      b[f] = make_float2(zb.x, -zb.y);
    }
    sfft128x2(a[0], b[0], a[1], b[1], ctx);
#pragma unroll
    for (int f = 0; f < 2; ++f) {
      if (wcol[f] < WF) {
        sImg[(2 * br) * WF + wcol[f]]     = packbf(a[f].x, -a[f].y);   // conj out
        sImg[(2 * br + 1) * WF + wcol[f]] = packbf(b[f].x, -b[f].y);
      }
    }
  }
  __syncthreads();

  // ---- phase 2: irfft rows (pair trick) -> crop -> scale -> +bias ----
  const float sc = 1.f / 16384.f;
  for (int batch = 0; batch < 8; ++batch) {      // row pairs 0..59 (+4 pad)
    float2 a[2], b[2]; int jpv[2];
#pragma unroll
    for (int f = 0; f < 2; ++f) {
      const int jp = batch * 8 + grp * 2 + f; jpv[f] = jp;
      const int jc = (jp < 60) ? jp : 59;
      const unsigned int* X0p = &sImg[(size_t)(2 * jc) * WF];
      const unsigned int* X1p = X0p + WF;
      float2 za, zb;
      if (l == 0) {
        za = make_float2(unpackbf(X0p[0]).x,  unpackbf(X1p[0]).x);    // DC
        zb = make_float2(unpackbf(X0p[64]).x, unpackbf(X1p[64]).x);   // Nyquist
      } else {
        float2 x0 = unpackbf(X0p[l]), x1 = unpackbf(X1p[l]);
        za = make_float2(x0.x - x1.y, x0.y + x1.x);                   // Z[l]
        const int mI = 64 - l;
        float2 y0 = unpackbf(X0p[mI]), y1 = unpackbf(X1p[mI]);
        zb = make_float2(y0.x + y1.y, y1.x - y0.y);                   // Z[64+l]
      }
      a[f] = make_float2(za.x, -za.y);           // conj in
      b[f] = make_float2(zb.x, -zb.y);
    }
    sfft128x2(a[0], b[0], a[1], b[1], ctx);
    const int n0 = 2 * br;
#pragma unroll
    for (int f = 0; f < 2; ++f) {
      const int jp = jpv[f];
      if (jp < 60 && n0 < WO) {
        // y[n] = conj(out): row0 = Re, row1 = -Im
        float2 r0 = make_float2(a[f].x * sc + bo,  b[f].x * sc + bo);
        float2 r1 = make_float2(-a[f].y * sc + bo, -b[f].y * sc + bo);
        *(float2*)(dst + (size_t)(2 * jp) * WO + n0)     = r0;
        *(float2*)(dst + (size_t)(2 * jp + 1) * WO + n0) = r1;
      }
    }
  }
}

// ---------------------------------------------------------------------------
extern "C" void kernel_launch(void* const* d_in, const int* in_sizes, int n_in,
                              void* d_out, int out_size, void* d_ws, size_t ws_size,
                              hipStream_t stream) {
  const float* signal = (const float*)d_in[0];
  const float* wr     = (const float*)d_in[1];
  const float* wi     = (const float*)d_in[2];
  const float* bias   = (const float*)d_in[3];
  float* out = (float*)d_out;

  unsigned int* sig_fr = (unsigned int*)d_out;   // 68.2 MB, dead before inv writes
  unsigned int* out_fr = (unsigned int*)d_ws;    // 136.3 MB
  (void)in_sizes; (void)n_in; (void)out_size; (void)ws_size;

  fwd_fft<<<NB * CIN, 256, 0, stream>>>(signal, sig_fr);
  spec_mm<<<2080, 512, 0, stream>>>(sig_fr, wr, wi, out_fr);
  inv_fft<<<NB * COUT, 256, 0, stream>>>(out_fr, bias, out);
}

// Round 17
// 449.980 us; speedup vs baseline: 1.0868x; 1.0784x over previous
//
#include <hip/hip_runtime.h>
#include <math.h>

#define DI __device__ __forceinline__

constexpr int Hh   = 128;
constexpr int Ww   = 128;
constexpr int WF   = 65;            // W/2+1
constexpr int NBIN = Hh * WF;       // 8320
constexpr int NB   = 32;            // batch
constexpr int CIN  = 64;
constexpr int COUT = 128;
constexpr int HO   = 120;
constexpr int WO   = 120;

typedef __bf16 bf16x8 __attribute__((ext_vector_type(8)));
typedef float  f32x16 __attribute__((ext_vector_type(16)));

// ---- bf16 pack/unpack (RNE) ----
DI unsigned int bfbits(float x) {
  unsigned int u = __float_as_uint(x);
  return (u + 0x7FFFu + ((u >> 16) & 1u)) >> 16;
}
DI unsigned int packbf(float re, float im) { return bfbits(re) | (bfbits(im) << 16); }
DI float2 unpackbf(unsigned int v) {
  return make_float2(__uint_as_float(v << 16), __uint_as_float(v & 0xFFFF0000u));
}

DI f32x16 MFMA32(uint4 a, uint4 b, f32x16 c) {
  return __builtin_amdgcn_mfma_f32_32x32x16_bf16(
      __builtin_bit_cast(bf16x8, a), __builtin_bit_cast(bf16x8, b), c, 0, 0, 0);
}
DI unsigned int rotneg(unsigned int x) { return ((x << 16) | (x >> 16)) ^ 0x80000000u; }
DI uint4 derive(uint4 s) {
  uint4 r; r.x = rotneg(s.x); r.y = rotneg(s.y); r.z = rotneg(s.z); r.w = rotneg(s.w);
  return r;
}

// LDS-only barrier: drains ds-ops (lgkmcnt) but leaves global loads (vmcnt)
// in flight across the barrier. sched_barrier fences (rule #18).
DI void lds_barrier() {
  __builtin_amdgcn_sched_barrier(0);
  asm volatile("s_waitcnt lgkmcnt(0)" ::: "memory");
  __builtin_amdgcn_sched_barrier(0);
  __builtin_amdgcn_s_barrier();
  __builtin_amdgcn_sched_barrier(0);
}

// ---------------------------------------------------------------------------
// Register/shuffle 128-pt DIF FFT (ILP-2), lane-select folded into per-lane
// constants. Lane l holds a=x[l], b=x[l+64].
// After: a = X[2*bitrev6(l)], b = X[2*bitrev6(l)+1].
// Inverse: conj in, same DIF, conj out.
// ---------------------------------------------------------------------------
DI int bitrev6(int l) {
  return ((l & 1) << 5) | ((l & 2) << 3) | ((l & 4) << 1) |
         ((l & 8) >> 1) | ((l & 16) >> 3) | ((l & 32) >> 5);
}
DI float2 cmul(float2 a, float2 b) {
  return make_float2(a.x * b.x - a.y * b.y, a.x * b.y + a.y * b.x);
}
DI float2 sxor(float2 v, int m) {
  return make_float2(__shfl_xor(v.x, m), __shfl_xor(v.y, m));
}
DI float bpermf(int addr, float v) {
  return __int_as_float(__builtin_amdgcn_ds_bpermute(addr, __float_as_int(v)));
}

struct FftCtx {
  float2 tw0;       // W128^l (stage h=64, both outputs kept)
  float2 tws[5];    // per-lane selected twiddle, stages h=32,16,8,4,2
  float  sgn[5];    // +1 on sum-lanes, -1 on diff-lanes
  float  sgn1;      // stage h=1
};
DI void twinit(FftCtx& c, int l) {
  float s_, c_;
  __sincosf(-(float)M_PI * (float)l / 64.f, &s_, &c_);
  c.tw0 = make_float2(c_, s_);
#pragma unroll
  for (int i = 0; i < 5; ++i) {
    const int h = 32 >> i;
    __sincosf(-(float)M_PI * (float)(l & (h - 1)) / (float)h, &s_, &c_);
    const bool hi = (l & h) != 0;
    c.tws[i] = hi ? make_float2(c_, s_) : make_float2(1.f, 0.f);
    c.sgn[i] = hi ? -1.f : 1.f;
  }
  c.sgn1 = (l & 1) ? -1.f : 1.f;
}
DI void stgf(float2& v, int m, float2 tw, float sgn) {
  float2 p = sxor(v, m);
  float2 t = make_float2(fmaf(sgn, v.x, p.x), fmaf(sgn, v.y, p.y));
  v = cmul(t, tw);
}
DI void stg1f(float2& v, float sgn) {
  float2 p = sxor(v, 1);
  v = make_float2(fmaf(sgn, v.x, p.x), fmaf(sgn, v.y, p.y));
}
DI void sfft128x2(float2& a0, float2& b0, float2& a1, float2& b1,
                  const FftCtx& c) {
  {
    float2 s = make_float2(a0.x + b0.x, a0.y + b0.y);
    float2 d = make_float2(a0.x - b0.x, a0.y - b0.y);
    a0 = s; b0 = cmul(d, c.tw0);
  }
  {
    float2 s = make_float2(a1.x + b1.x, a1.y + b1.y);
    float2 d = make_float2(a1.x - b1.x, a1.y - b1.y);
    a1 = s; b1 = cmul(d, c.tw0);
  }
#pragma unroll
  for (int i = 0; i < 5; ++i) {
    const int h = 32 >> i;
    stgf(a0, h, c.tws[i], c.sgn[i]); stgf(a1, h, c.tws[i], c.sgn[i]);
    stgf(b0, h, c.tws[i], c.sgn[i]); stgf(b1, h, c.tws[i], c.sgn[i]);
  }
  stg1f(a0, c.sgn1); stg1f(a1, c.sgn1); stg1f(b0, c.sgn1); stg1f(b1, c.sgn1);
}

// ---------------------------------------------------------------------------
// Forward: one block (256 thr) per (b, i). real 128x128 -> bf16 complex 128x65.
// rfft unpack fully in-register via ds_bpermute. (FROZEN)
// ---------------------------------------------------------------------------
__global__ __launch_bounds__(256) void fwd_fft(const float* __restrict__ sig,
                                               unsigned int* __restrict__ sf) {
  __shared__ unsigned int sImg[NBIN];                       // 33280 B

  const int t = threadIdx.x, grp = t >> 6, l = t & 63;
  const size_t img = blockIdx.x;
  const float* src = sig + img * (size_t)(Hh * Ww);
  unsigned int* dst = sf + img * (size_t)NBIN;

  FftCtx ctx; twinit(ctx, l);
  const int br = bitrev6(l);
  const int sk4 = bitrev6(l >> 1) * 4;                 // holder of Z[l]
  const int im  = (128 - l) & 127;
  const int sm4 = bitrev6(im >> 1) * 4;                // holder of Z[128-l]
  const bool podd = (l & 1) != 0;

  // ---- phase 1: row rfft (two real rows per complex FFT), ILP-2 ----
  for (int batch = 0; batch < 8; ++batch) {
    float2 a[2], b[2];
#pragma unroll
    for (int f = 0; f < 2; ++f) {
      const int jp = batch * 8 + grp * 2 + f;               // row pair 0..63
      const float* r0 = src + (size_t)(2 * jp) * Ww;
      a[f] = make_float2(r0[l],      r0[Ww + l]);
      b[f] = make_float2(r0[64 + l], r0[Ww + 64 + l]);
    }
    sfft128x2(a[0], b[0], a[1], b[1], ctx);
#pragma unroll
    for (int f = 0; f < 2; ++f) {
      const int jp = batch * 8 + grp * 2 + f;
      float axk = bpermf(sk4, a[f].x), ayk = bpermf(sk4, a[f].y);
      float bxk = bpermf(sk4, b[f].x), byk = bpermf(sk4, b[f].y);
      float axm = bpermf(sm4, a[f].x), aym = bpermf(sm4, a[f].y);
      float bxm = bpermf(sm4, b[f].x), bym = bpermf(sm4, b[f].y);
      float z64x = bpermf(4, a[f].x),  z64y = bpermf(4, a[f].y);   // Z[64] in lane 1.a
      float2 Zk = podd ? make_float2(bxk, byk) : make_float2(axk, ayk);
      float2 Zm = podd ? make_float2(bxm, bym) : make_float2(axm, aym);
      sImg[(2 * jp) * WF + l]     = packbf(0.5f * (Zk.x + Zm.x), 0.5f * (Zk.y - Zm.y));
      sImg[(2 * jp + 1) * WF + l] = packbf(0.5f * (Zk.y + Zm.y), 0.5f * (Zm.x - Zk.x));
      if (l == 0) {
        sImg[(2 * jp) * WF + 64]     = packbf(z64x, 0.f);
        sImg[(2 * jp + 1) * WF + 64] = packbf(z64y, 0.f);
      }
    }
  }
  __syncthreads();

  // ---- phase 2: complex FFT along H per column, in-register ----
  for (int batch = 0; batch < 9; ++batch) {
    float2 a[2], b[2]; int wcol[2];
#pragma unroll
    for (int f = 0; f < 2; ++f) {
      const int w = batch * 8 + grp * 2 + f; wcol[f] = w;
      const int wc = (w < WF) ? w : (WF - 1);
      a[f] = unpackbf(sImg[l * WF + wc]);
      b[f] = unpackbf(sImg[(l + 64) * WF + wc]);
    }
    sfft128x2(a[0], b[0], a[1], b[1], ctx);
#pragma unroll
    for (int f = 0; f < 2; ++f) {
      if (wcol[f] < WF) {
        sImg[(2 * br) * WF + wcol[f]]     = packbf(a[f].x, a[f].y);
        sImg[(2 * br + 1) * WF + wcol[f]] = packbf(b[f].x, b[f].y);
      }
    }
  }
  __syncthreads();

  const uint4* s4 = (const uint4*)sImg;
  uint4* d4 = (uint4*)dst;
  for (int idx = t; idx < NBIN / 4; idx += 256) d4[idx] = s4[idx];
}

// ---------------------------------------------------------------------------
// Spectral contraction via 32x32x16 MFMA (r13 geometry/order, FROZEN) plus an
// LDS-transposed epilogue: acc -> LDS [b16][o][bin] -> coalesced uint4 stores
// (64-B segments, 4x fewer store insts vs 32 scattered 8-B stores/lane).
// Staging arena is reused for the epilogue (no LDS growth).
// ---------------------------------------------------------------------------
constexpr int PT    = 16;
constexpr int PLANE = 260;
constexpr int EPB   = 524;           // epilogue b-stride (4-aligned, bank-rotating)

__global__ __launch_bounds__(512, 4) void spec_mm(const unsigned int* __restrict__ sf,
                                                  const float* __restrict__ wr,
                                                  const float* __restrict__ wi,
                                                  unsigned int* __restrict__ of) {
  __shared__ unsigned int arena[2 * PT * PLANE + 64];   // 33.5 KB
  unsigned int* wbuf = arena;                 // [PT*PLANE]
  unsigned int* sbuf = arena + PT * PLANE;    // [PT*PLANE]

  const int t = threadIdx.x;
  const int bid = blockIdx.x;
  const int swz = (bid & 7) * 260 + (bid >> 3);
  const int o0 = (swz & 3) * 32;
  const int p0 = (swz >> 2) * PT;

  const int po = t & 3;
  const int ii = (t >> 2) & 7;
  const int rl = (t >> 5) & 15;

  const float* wrp0 = wr + ((size_t)(o0 + rl) * CIN + ii) * NBIN + p0 + po * 4;
  const float* wip0 = wi + ((size_t)(o0 + rl) * CIN + ii) * NBIN + p0 + po * 4;
  const unsigned int* sfp0 = sf + ((size_t)rl * CIN + ii) * NBIN + p0 + po * 4;
  const size_t rowAdv = (size_t)16 * CIN * NBIN;

  auto slotOf = [](int row, int i) {
    return ((((row * 2) + (i >> 2)) ^ ((row >> 2) & 7)) << 2) + (i & 3);
  };
  const int slotLo = slotOf(rl, ii);
  const int slotHi = slotOf(rl + 16, ii);

  const int l = t & 63, wv = t >> 6;
  const int lr = l & 31, lq = l >> 5;
  const int moff = ((((lr * 2) + lq) ^ ((lr >> 2) & 7)) << 2);
  const int pA = 2 * wv, pB = 2 * wv + 1;

  f32x16 aR0 = {}, aI0 = {}, aR1 = {}, aI1 = {};

  float4 w0r, w1r, w0i, w1i; uint4 s0v, s1v;
  {
    w0r = *(const float4*)(wrp0);          w1r = *(const float4*)(wrp0 + rowAdv);
    w0i = *(const float4*)(wip0);          w1i = *(const float4*)(wip0 + rowAdv);
    s0v = *(const uint4*)(sfp0);           s1v = *(const uint4*)(sfp0 + rowAdv);
  }

  for (int kq = 0; kq < 8; ++kq) {
    // ---- pack current chunk regs -> LDS ----
    const float* a0 = (const float*)&w0r;  const float* a1 = (const float*)&w1r;
    const float* b0 = (const float*)&w0i;  const float* b1 = (const float*)&w1i;
    const unsigned int* u0 = (const unsigned int*)&s0v;
    const unsigned int* u1 = (const unsigned int*)&s1v;
#pragma unroll
    for (int j = 0; j < 4; ++j) {
      const int pp = (po * 4 + j) * PLANE;
      wbuf[pp + slotLo] = packbf(a0[j], -b0[j]);
      wbuf[pp + slotHi] = packbf(a1[j], -b1[j]);
      sbuf[pp + slotLo] = u0[j];
      sbuf[pp + slotHi] = u1[j];
    }
    // ---- issue next chunk's loads; stay in flight across barriers ----
    if (kq < 7) {
      const size_t adv = (size_t)(kq + 1) * 8 * NBIN;
      w0r = *(const float4*)(wrp0 + adv);  w1r = *(const float4*)(wrp0 + adv + rowAdv);
      w0i = *(const float4*)(wip0 + adv);  w1i = *(const float4*)(wip0 + adv + rowAdv);
      s0v = *(const uint4*)(sfp0 + adv);   s1v = *(const uint4*)(sfp0 + adv + rowAdv);
    }
    lds_barrier();

    {
      const uint4 a = *(const uint4*)&wbuf[pA * PLANE + moff];
      const uint4 s = *(const uint4*)&sbuf[pA * PLANE + moff];
      aR0 = MFMA32(a, s, aR0);
      aI0 = MFMA32(a, derive(s), aI0);
    }
    {
      const uint4 a = *(const uint4*)&wbuf[pB * PLANE + moff];
      const uint4 s = *(const uint4*)&sbuf[pB * PLANE + moff];
      aR1 = MFMA32(a, s, aR1);
      aI1 = MFMA32(a, derive(s), aI1);
    }
    lds_barrier();
  }

  // ---- epilogue: transpose acc through LDS, coalesced 16-B stores ----
  // lbuf layout: [b16][EPB] with (o,bin) packed as o*16+bin inside a row.
  unsigned int* lbuf = arena;    // staging LDS is dead past the last barrier
#pragma unroll
  for (int h = 0; h < 2; ++h) {
    if ((lr >> 4) == h) {
      const int b16 = lr & 15;
#pragma unroll
      for (int r = 0; r < 16; ++r) {
        const int oo = (r & 3) + 8 * (r >> 2) + 4 * lq;
        uint2 v;
        v.x = packbf(aR0[r], aI0[r]);
        v.y = packbf(aR1[r], aI1[r]);
        *(uint2*)&lbuf[b16 * EPB + oo * 16 + 2 * wv] = v;
      }
    }
    lds_barrier();
    // 16 b x 32 o x 16 bins = 8192 u32 = 2048 uint4; 512 thr x 4 iters
#pragma unroll
    for (int it = 0; it < 4; ++it) {
      const int idx = it * 512 + t;
      const int bin4 = idx & 3;
      const int oo = (idx >> 2) & 31;
      const int bb = idx >> 7;
      const uint4 v = *(const uint4*)&lbuf[bb * EPB + oo * 16 + bin4 * 4];
      const size_t b = (size_t)(h * 16 + bb);
      *(uint4*)(of + (b * COUT + o0 + oo) * NBIN + p0 + bin4 * 4) = v;
    }
    if (h == 0) lds_barrier();
  }
}

// ---------------------------------------------------------------------------
// Inverse: one block (256 thr) per (b, o). bf16 128x65 -> real 120x120 (+bias).
// y = conj(DIF(conj z)) / 16384; rows write straight to global. (FROZEN)
// ---------------------------------------------------------------------------
__global__ __launch_bounds__(256) void inv_fft(const unsigned int* __restrict__ of,
                                               const float* __restrict__ bias,
                                               float* __restrict__ out) {
  __shared__ unsigned int sImg[NBIN];

  const int t = threadIdx.x, grp = t >> 6, l = t & 63;
  const size_t img = blockIdx.x;                 // b*COUT + o
  const unsigned int* src = of + img * (size_t)NBIN;
  float* dst = out + img * (size_t)(HO * WO);
  const float bo = bias[img & (COUT - 1)];

  FftCtx ctx; twinit(ctx, l);
  const int br = bitrev6(l);

  const uint4* s4 = (const uint4*)src;
  uint4* d4 = (uint4*)sImg;
  for (int idx = t; idx < NBIN / 4; idx += 256) d4[idx] = s4[idx];
  __syncthreads();

  // ---- phase 1: inverse FFT along H per column (unscaled) ----
  for (int batch = 0; batch < 9; ++batch) {
    float2 a[2], b[2]; int wcol[2];
#pragma unroll
    for (int f = 0; f < 2; ++f) {
      const int w = batch * 8 + grp * 2 + f; wcol[f] = w;
      const int wc = (w < WF) ? w : (WF - 1);
      float2 za = unpackbf(sImg[l * WF + wc]);
      float2 zb = unpackbf(sImg[(l + 64) * WF + wc]);
      a[f] = make_float2(za.x, -za.y);           // conj in
      b[f] = make_float2(zb.x, -zb.y);
    }
    sfft128x2(a[0], b[0], a[1], b[1], ctx);
#pragma unroll
    for (int f = 0; f < 2; ++f) {
      if (wcol[f] < WF) {
        sImg[(2 * br) * WF + wcol[f]]     = packbf(a[f].x, -a[f].y);   // conj out
        sImg[(2 * br + 1) * WF + wcol[f]] = packbf(b[f].x, -b[f].y);
      }
    }
  }
  __syncthreads();

  // ---- phase 2: irfft rows (pair trick) -> crop -> scale -> +bias ----
  const float sc = 1.f / 16384.f;
  for (int batch = 0; batch < 8; ++batch) {      // row pairs 0..59 (+4 pad)
    float2 a[2], b[2]; int jpv[2];
#pragma unroll
    for (int f = 0; f < 2; ++f) {
      const int jp = batch * 8 + grp * 2 + f; jpv[f] = jp;
      const int jc = (jp < 60) ? jp : 59;
      const unsigned int* X0p = &sImg[(size_t)(2 * jc) * WF];
      const unsigned int* X1p = X0p + WF;
      float2 za, zb;
      if (l == 0) {
        za = make_float2(unpackbf(X0p[0]).x,  unpackbf(X1p[0]).x);    // DC
        zb = make_float2(unpackbf(X0p[64]).x, unpackbf(X1p[64]).x);   // Nyquist
      } else {
        float2 x0 = unpackbf(X0p[l]), x1 = unpackbf(X1p[l]);
        za = make_float2(x0.x - x1.y, x0.y + x1.x);                   // Z[l]
        const int mI = 64 - l;
        float2 y0 = unpackbf(X0p[mI]), y1 = unpackbf(X1p[mI]);
        zb = make_float2(y0.x + y1.y, y1.x - y0.y);                   // Z[64+l]
      }
      a[f] = make_float2(za.x, -za.y);           // conj in
      b[f] = make_float2(zb.x, -zb.y);
    }
    sfft128x2(a[0], b[0], a[1], b[1], ctx);
    const int n0 = 2 * br;
#pragma unroll
    for (int f = 0; f < 2; ++f) {
      const int jp = jpv[f];
      if (jp < 60 && n0 < WO) {
        // y[n] = conj(out): row0 = Re, row1 = -Im
        float2 r0 = make_float2(a[f].x * sc + bo,  b[f].x * sc + bo);
        float2 r1 = make_float2(-a[f].y * sc + bo, -b[f].y * sc + bo);
        *(float2*)(dst + (size_t)(2 * jp) * WO + n0)     = r0;
        *(float2*)(dst + (size_t)(2 * jp + 1) * WO + n0) = r1;
      }
    }
  }
}

// ---------------------------------------------------------------------------
extern "C" void kernel_launch(void* const* d_in, const int* in_sizes, int n_in,
                              void* d_out, int out_size, void* d_ws, size_t ws_size,
                              hipStream_t stream) {
  const float* signal = (const float*)d_in[0];
  const float* wr     = (const float*)d_in[1];
  const float* wi     = (const float*)d_in[2];
  const float* bias   = (const float*)d_in[3];
  float* out = (float*)d_out;

  unsigned int* sig_fr = (unsigned int*)d_out;   // 68.2 MB, dead before inv writes
  unsigned int* out_fr = (unsigned int*)d_ws;    // 136.3 MB
  (void)in_sizes; (void)n_in; (void)out_size; (void)ws_size;

  fwd_fft<<<NB * CIN, 256, 0, stream>>>(signal, sig_fr);
  spec_mm<<<2080, 512, 0, stream>>>(sig_fr, wr, wi, out_fr);
  inv_fft<<<NB * COUT, 256, 0, stream>>>(out_fr, bias, out);
}